// Round 15
// baseline (1664.746 us; speedup 1.0000x reference)
//
#include <hip/hip_runtime.h>

// GCN forward: 3x GCNConv (128->64->64->2) + linear head (2->16).
// N=100000 nodes, E=1600000 edges (+self-loops handled analytically).
// Preprocessing: coarse bucket sort ONLY (128-node buckets) - the fine
// per-node sort is gone. Aggregation is EDGE-PARALLEL: one block per bucket,
// fp32 LDS accumulators acc[128][64], ds_add_f32 per edge (no per-node
// dependency chain -> deep load pipelining; round 14 showed the wave-per-node
// gather is latency-chain-bound at ~25 in-flight loads/CU).
// T rows are int16 (128B = 2 lines) with per-row scales fused into the
// transform GEMM (validated 4.88e-4 vs 2.66e-3 threshold).
// HISTORY: half-wave/2-rows-per-load gather = ~3e-3 absmax regardless of
// dtype (structural bug, banned). SGPR-indexed rs[] = s_load scalar-cache
// thrash (banned). dis[] pre-folded: T'[v]=dis[v]*t[v].

#define NF 128
#define NH 64
#define NPB 128      // nodes per coarse bucket (bucket = dst >> 7)
#define MAXNB 1024   // max coarse buckets (N < 131072)
#define A1G 1024     // grid for coarse count/scatter (must match between them)

// Zero coarse counters + detect int64 vs int32 edge_index layout.
__global__ void k_init0(const int* __restrict__ ei, int* __restrict__ fmt,
                        int* __restrict__ ccnt, int nb16) {
    int i = blockIdx.x * 256 + threadIdx.x;
    if (i < nb16) ccnt[i] = 0;
    if (i == 0) {
        int f = 1;
        #pragma unroll
        for (int k = 1; k < 32; k += 2) if (ei[k] != 0) f = 0;
        *fmt = f;   // 1 => int64 (stride 2 in int32 words), 0 => int32
    }
}

// Coarse count: LDS histogram per block, then reserve per-(block,bucket) space
// with ONE padded global atomic per bucket per block (line-parallel).
__global__ void __launch_bounds__(256) k_coarse(
        const int* __restrict__ ei, const int* __restrict__ fmt,
        int* __restrict__ ccnt, int* __restrict__ blockbase, int E, int NB) {
    __shared__ int h[MAXNB];
    int sh = *fmt;
    for (int i = threadIdx.x; i < NB; i += 256) h[i] = 0;
    __syncthreads();
    for (long long e = (long long)blockIdx.x * 256 + threadIdx.x; e < E;
         e += (long long)A1G * 256) {
        int d = ei[(long long)(E + e) << sh];
        atomicAdd(&h[d >> 7], 1);
    }
    __syncthreads();
    for (int b = threadIdx.x; b < NB; b += 256) {
        int c = h[b];
        int base = (c > 0) ? atomicAdd(&ccnt[b * 16], c) : 0;
        blockbase[(long long)blockIdx.x * NB + b] = base;
    }
}

// Exclusive scan of the NB coarse counts (single block, NB <= 1024).
__global__ void __launch_bounds__(1024) k_cscan(
        const int* __restrict__ ccnt, int* __restrict__ cstart, int NB) {
    __shared__ int s[1024];
    int t = threadIdx.x;
    int c = (t < NB) ? ccnt[t * 16] : 0;
    s[t] = c;
    __syncthreads();
    for (int off = 1; off < 1024; off <<= 1) {
        int v = s[t];
        int u = (t >= off) ? s[t - off] : 0;
        __syncthreads();
        s[t] = v + u;
        __syncthreads();
    }
    if (t < NB) cstart[t] = s[t] - c;
}

// Coarse scatter: same grid-stride partition as k_coarse, so this block's
// per-bucket totals equal its reservation. Per-bucket write bases staged in
// LDS once. Local ranks via LDS atomics. Edge packed as src | (dst&127)<<17.
__global__ void __launch_bounds__(256) k_cscatter(
        const int* __restrict__ ei, const int* __restrict__ fmt,
        const int* __restrict__ cstart, const int* __restrict__ blockbase,
        int* __restrict__ pairs, int E, int NB) {
    __shared__ int h[MAXNB];
    __shared__ int bb[MAXNB];
    int sh = *fmt;
    for (int i = threadIdx.x; i < NB; i += 256) {
        h[i] = 0;
        bb[i] = cstart[i] + blockbase[(long long)blockIdx.x * NB + i];
    }
    __syncthreads();
    for (long long e = (long long)blockIdx.x * 256 + threadIdx.x; e < E;
         e += (long long)A1G * 256) {
        int s = ei[(long long)e << sh];
        int d = ei[(long long)(E + e) << sh];
        int b = d >> 7;
        int r = atomicAdd(&h[b], 1);
        pairs[bb[b] + r] = s | ((d & 127) << 17);
    }
}

// Per-bucket degree histogram (contiguous pairs read) -> dis = rsqrt(1+deg).
__global__ void __launch_bounds__(256) k_deg(
        const int* __restrict__ pairs, const int* __restrict__ ccnt,
        const int* __restrict__ cstart, float* __restrict__ dis, int N) {
    __shared__ int h[NPB];
    int t = threadIdx.x;
    if (t < NPB) h[t] = 0;
    __syncthreads();
    int cs = cstart[blockIdx.x], ec = ccnt[blockIdx.x * 16];
    for (int i = t; i < ec; i += 256) atomicAdd(&h[pairs[cs + i] >> 17], 1);
    __syncthreads();
    int nd = blockIdx.x * NPB + t;
    if (t < NPB && nd < N) dis[nd] = rsqrtf(1.0f + (float)h[t]);
}

// T16[n,NH] (int16) = quant_rowwise( dis[n] * (X[n,K] @ W[K,NH]) );
// rs[n] = rowmax/32767. 64 rows/block, 4x4 per thread; per-row max via LDS
// atomicMax across the 16 threads sharing a row (abs values: int cmp valid).
template<int K>
__global__ void __launch_bounds__(256) k_gemm(
        const float* __restrict__ X, const float* __restrict__ W,
        const float* __restrict__ dis, short* __restrict__ T16,
        float* __restrict__ rs, int n) {
    constexpr int KP = K + 4;
    __shared__ float xs[64 * KP];
    __shared__ float Ws[K * NH];
    __shared__ int rmax[64];
    if (threadIdx.x < 64) rmax[threadIdx.x] = 0;
    for (int i = threadIdx.x; i < K * NH / 4; i += 256)
        ((float4*)Ws)[i] = ((const float4*)W)[i];
    long long rowbase = (long long)blockIdx.x * 64;
    const float4* X4 = (const float4*)(X + rowbase * K);
    long long lim4 = ((long long)n * K - rowbase * K) >> 2;  // remaining float4s
    for (int i = threadIdx.x; i < 16 * K; i += 256) {
        float4 v = (i < lim4) ? X4[i] : make_float4(0.f, 0.f, 0.f, 0.f);
        int r = i / (K / 4), kk = (i % (K / 4)) * 4;
        *(float4*)&xs[r * KP + kk] = v;
    }
    __syncthreads();
    int c0 = (threadIdx.x & 15) * 4;
    int r0 = (threadIdx.x >> 4) * 4;
    const float* x0 = &xs[(r0 + 0) * KP];
    const float* x1 = &xs[(r0 + 1) * KP];
    const float* x2 = &xs[(r0 + 2) * KP];
    const float* x3 = &xs[(r0 + 3) * KP];
    float4 a0{0,0,0,0}, a1{0,0,0,0}, a2{0,0,0,0}, a3{0,0,0,0};
    #pragma unroll 4
    for (int k = 0; k < K; ++k) {
        float4 w = *(const float4*)&Ws[k * NH + c0];
        float v0 = x0[k], v1 = x1[k], v2 = x2[k], v3 = x3[k];
        a0.x += v0 * w.x; a0.y += v0 * w.y; a0.z += v0 * w.z; a0.w += v0 * w.w;
        a1.x += v1 * w.x; a1.y += v1 * w.y; a1.z += v1 * w.z; a1.w += v1 * w.w;
        a2.x += v2 * w.x; a2.y += v2 * w.y; a2.z += v2 * w.z; a2.w += v2 * w.w;
        a3.x += v3 * w.x; a3.y += v3 * w.y; a3.z += v3 * w.z; a3.w += v3 * w.w;
    }
    int row = (int)rowbase + r0;
    float d0 = (row + 0 < n) ? dis[row + 0] : 0.0f;
    float d1 = (row + 1 < n) ? dis[row + 1] : 0.0f;
    float d2 = (row + 2 < n) ? dis[row + 2] : 0.0f;
    float d3 = (row + 3 < n) ? dis[row + 3] : 0.0f;
    a0.x *= d0; a0.y *= d0; a0.z *= d0; a0.w *= d0;
    a1.x *= d1; a1.y *= d1; a1.z *= d1; a1.w *= d1;
    a2.x *= d2; a2.y *= d2; a2.z *= d2; a2.w *= d2;
    a3.x *= d3; a3.y *= d3; a3.z *= d3; a3.w *= d3;
    float m0 = fmaxf(fmaxf(fabsf(a0.x), fabsf(a0.y)), fmaxf(fabsf(a0.z), fabsf(a0.w)));
    float m1 = fmaxf(fmaxf(fabsf(a1.x), fabsf(a1.y)), fmaxf(fabsf(a1.z), fabsf(a1.w)));
    float m2 = fmaxf(fmaxf(fabsf(a2.x), fabsf(a2.y)), fmaxf(fabsf(a2.z), fabsf(a2.w)));
    float m3 = fmaxf(fmaxf(fabsf(a3.x), fabsf(a3.y)), fmaxf(fabsf(a3.z), fabsf(a3.w)));
    atomicMax(&rmax[r0 + 0], __float_as_int(m0));
    atomicMax(&rmax[r0 + 1], __float_as_int(m1));
    atomicMax(&rmax[r0 + 2], __float_as_int(m2));
    atomicMax(&rmax[r0 + 3], __float_as_int(m3));
    __syncthreads();
    float M0 = __int_as_float(rmax[r0 + 0]);
    float M1 = __int_as_float(rmax[r0 + 1]);
    float M2 = __int_as_float(rmax[r0 + 2]);
    float M3 = __int_as_float(rmax[r0 + 3]);
    float i0 = 32767.0f / fmaxf(M0, 1e-20f);
    float i1 = 32767.0f / fmaxf(M1, 1e-20f);
    float i2 = 32767.0f / fmaxf(M2, 1e-20f);
    float i3 = 32767.0f / fmaxf(M3, 1e-20f);
    const float ks = 1.0f / 32767.0f;
    if (row + 0 < n) {
        short4 q = { (short)__float2int_rn(a0.x * i0), (short)__float2int_rn(a0.y * i0),
                     (short)__float2int_rn(a0.z * i0), (short)__float2int_rn(a0.w * i0) };
        *(short4*)&T16[(long long)(row + 0) * NH + c0] = q;
        if (c0 == 0) rs[row + 0] = M0 * ks;
    }
    if (row + 1 < n) {
        short4 q = { (short)__float2int_rn(a1.x * i1), (short)__float2int_rn(a1.y * i1),
                     (short)__float2int_rn(a1.z * i1), (short)__float2int_rn(a1.w * i1) };
        *(short4*)&T16[(long long)(row + 1) * NH + c0] = q;
        if (c0 == 0) rs[row + 1] = M1 * ks;
    }
    if (row + 2 < n) {
        short4 q = { (short)__float2int_rn(a2.x * i2), (short)__float2int_rn(a2.y * i2),
                     (short)__float2int_rn(a2.z * i2), (short)__float2int_rn(a2.w * i2) };
        *(short4*)&T16[(long long)(row + 2) * NH + c0] = q;
        if (c0 == 0) rs[row + 2] = M2 * ks;
    }
    if (row + 3 < n) {
        short4 q = { (short)__float2int_rn(a3.x * i3), (short)__float2int_rn(a3.y * i3),
                     (short)__float2int_rn(a3.z * i3), (short)__float2int_rn(a3.w * i3) };
        *(short4*)&T16[(long long)(row + 3) * NH + c0] = q;
        if (c0 == 0) rs[row + 3] = M3 * ks;
    }
}

// Edge-parallel aggregation: one block per 128-node bucket, fp32 LDS
// accumulators. Waves stream contiguous pairs words; per edge: readlane
// (word + scale bits), saddr int16 row load, ds_add_f32 into acc row.
// EPI=0: O = di*(acc + self) + b (full rows).  EPI=1: fused tanh @ W2 -> t2.
template<int EPI>
__global__ void __launch_bounds__(256) k_agg(
        const short* __restrict__ T, const float* __restrict__ rs,
        const int* __restrict__ pairs, const int* __restrict__ ccnt,
        const int* __restrict__ cstart, const float* __restrict__ dis,
        const float* __restrict__ b, const float* __restrict__ W2,
        float* __restrict__ O, float2* __restrict__ t2, int N) {
    __shared__ float acc[NPB * NH];   // 32 KB
    int tid = threadIdx.x;
    int lane = tid & 63;
    int wv = tid >> 6;
    for (int i = tid; i < NPB * NH; i += 256) acc[i] = 0.0f;
    __syncthreads();
    int cs = cstart[blockIdx.x], ec = ccnt[blockIdx.x * 16];
    for (int base = wv * 64; base < ec; base += 256) {
        int m = ec - base; if (m > 64) m = 64;
        int w = 0; float fv = 0.0f;
        if (lane < m) { w = pairs[cs + base + lane]; fv = rs[w & 0x1FFFF]; }
        int fvb = __float_as_int(fv);
        int j = 0;
        for (; j + 7 < m; j += 8) {
            int w0 = __builtin_amdgcn_readlane(w, j + 0);
            int w1 = __builtin_amdgcn_readlane(w, j + 1);
            int w2 = __builtin_amdgcn_readlane(w, j + 2);
            int w3 = __builtin_amdgcn_readlane(w, j + 3);
            int w4 = __builtin_amdgcn_readlane(w, j + 4);
            int w5 = __builtin_amdgcn_readlane(w, j + 5);
            int w6 = __builtin_amdgcn_readlane(w, j + 6);
            int w7 = __builtin_amdgcn_readlane(w, j + 7);
            float f0 = __int_as_float(__builtin_amdgcn_readlane(fvb, j + 0));
            float f1 = __int_as_float(__builtin_amdgcn_readlane(fvb, j + 1));
            float f2 = __int_as_float(__builtin_amdgcn_readlane(fvb, j + 2));
            float f3 = __int_as_float(__builtin_amdgcn_readlane(fvb, j + 3));
            float f4 = __int_as_float(__builtin_amdgcn_readlane(fvb, j + 4));
            float f5 = __int_as_float(__builtin_amdgcn_readlane(fvb, j + 5));
            float f6 = __int_as_float(__builtin_amdgcn_readlane(fvb, j + 6));
            float f7 = __int_as_float(__builtin_amdgcn_readlane(fvb, j + 7));
            short v0 = (T + (w0 & 0x1FFFF) * NH)[lane];
            short v1 = (T + (w1 & 0x1FFFF) * NH)[lane];
            short v2 = (T + (w2 & 0x1FFFF) * NH)[lane];
            short v3 = (T + (w3 & 0x1FFFF) * NH)[lane];
            short v4 = (T + (w4 & 0x1FFFF) * NH)[lane];
            short v5 = (T + (w5 & 0x1FFFF) * NH)[lane];
            short v6 = (T + (w6 & 0x1FFFF) * NH)[lane];
            short v7 = (T + (w7 & 0x1FFFF) * NH)[lane];
            atomicAdd(&acc[(w0 >> 17) * NH + lane], f0 * (float)v0);
            atomicAdd(&acc[(w1 >> 17) * NH + lane], f1 * (float)v1);
            atomicAdd(&acc[(w2 >> 17) * NH + lane], f2 * (float)v2);
            atomicAdd(&acc[(w3 >> 17) * NH + lane], f3 * (float)v3);
            atomicAdd(&acc[(w4 >> 17) * NH + lane], f4 * (float)v4);
            atomicAdd(&acc[(w5 >> 17) * NH + lane], f5 * (float)v5);
            atomicAdd(&acc[(w6 >> 17) * NH + lane], f6 * (float)v6);
            atomicAdd(&acc[(w7 >> 17) * NH + lane], f7 * (float)v7);
        }
        for (; j < m; ++j) {
            int wj = __builtin_amdgcn_readlane(w, j);
            float f = __int_as_float(__builtin_amdgcn_readlane(fvb, j));
            short v = (T + (wj & 0x1FFFF) * NH)[lane];
            atomicAdd(&acc[(wj >> 17) * NH + lane], f * (float)v);
        }
    }
    __syncthreads();
    int node0 = blockIdx.x * NPB;
    if (EPI == 0) {
        for (int i = tid; i < NPB * NH; i += 256) {
            int nd = node0 + (i >> 6);
            if (nd >= N) break;
            int ln = i & 63;
            float self = rs[nd] * (float)T[nd * NH + ln];
            O[(long long)nd * NH + ln] = dis[nd] * (acc[i] + self) + b[ln];
        }
    } else {
        float2 w2v = ((const float2*)W2)[lane];
        for (int k = wv; k < NPB; k += 4) {
            int nd = node0 + k;
            if (nd >= N) continue;
            float di = dis[nd];
            float self = rs[nd] * (float)T[nd * NH + lane];
            float t = tanhf(di * (acc[k * NH + lane] + self) + b[lane]);
            float p0 = t * w2v.x, p1 = t * w2v.y;
            #pragma unroll
            for (int msk = 32; msk; msk >>= 1) {
                p0 += __shfl_xor(p0, msk, 64);
                p1 += __shfl_xor(p1, msk, 64);
            }
            if (lane == 0) t2[nd] = make_float2(di * p0, di * p1);
        }
    }
}

// Layer-2 aggregation + head, edge-parallel (thread per edge, LDS acc[128][2]):
// agg2 = di*(t2self + acc) + b2; emb = tanh(agg2); out = emb @ Wc + bc.
__global__ void __launch_bounds__(256) k_agg2(
        const float2* __restrict__ t2, const int* __restrict__ pairs,
        const int* __restrict__ ccnt, const int* __restrict__ cstart,
        const float* __restrict__ dis, const float* __restrict__ b2,
        const float* __restrict__ Wc, const float* __restrict__ bc,
        float* __restrict__ out, float* __restrict__ emb, int N) {
    __shared__ float a0s[NPB], a1s[NPB];
    __shared__ float e0s[NPB], e1s[NPB];
    __shared__ float Wcs[32], bcs[16];
    int tid = threadIdx.x;
    if (tid < NPB) { a0s[tid] = 0.f; a1s[tid] = 0.f; }
    if (tid < 32) Wcs[tid] = Wc[tid];
    if (tid < 16) bcs[tid] = bc[tid];
    __syncthreads();
    int cs = cstart[blockIdx.x], ec = ccnt[blockIdx.x * 16];
    for (int i = tid; i < ec; i += 256) {
        int w = pairs[cs + i];
        float2 v = t2[w & 0x1FFFF];
        int d = w >> 17;
        atomicAdd(&a0s[d], v.x);
        atomicAdd(&a1s[d], v.y);
    }
    __syncthreads();
    int node0 = blockIdx.x * NPB;
    if (tid < NPB) {
        int nd = node0 + tid;
        if (nd < N) {
            float di = dis[nd];
            float2 self = t2[nd];
            float e0 = tanhf(di * (a0s[tid] + self.x) + b2[0]);
            float e1 = tanhf(di * (a1s[tid] + self.y) + b2[1]);
            e0s[tid] = e0; e1s[tid] = e1;
            *(float2*)&emb[(long long)nd * 2] = make_float2(e0, e1);
        }
    }
    __syncthreads();
    for (int i = tid; i < NPB * 16; i += 256) {
        int k = i >> 4, c = i & 15;
        int nd = node0 + k;
        if (nd >= N) break;
        out[(long long)nd * 16 + c]
            = e0s[k] * Wcs[c] + e1s[k] * Wcs[16 + c] + bcs[c];
    }
}

extern "C" void kernel_launch(void* const* d_in, const int* in_sizes, int n_in,
                              void* d_out, int out_size, void* d_ws, size_t ws_size,
                              hipStream_t stream) {
    const float* x  = (const float*)d_in[0];
    const int*   ei = (const int*)  d_in[1];
    const float* W0 = (const float*)d_in[2];
    const float* b0 = (const float*)d_in[3];
    const float* W1 = (const float*)d_in[4];
    const float* b1 = (const float*)d_in[5];
    const float* W2 = (const float*)d_in[6];
    const float* b2 = (const float*)d_in[7];
    const float* Wc = (const float*)d_in[8];
    const float* bc = (const float*)d_in[9];

    int N = in_sizes[0] / NF;
    int E = in_sizes[1] / 2;
    int NB = (N + NPB - 1) / NPB;   // 782 for N=100000 (must be <= MAXNB)

    float* out = (float*)d_out;                    // [N,16]
    float* emb = out + (long long)N * 16;          // [N,2]

    // workspace: T16[N*64 int16 = 12.8MB] | Bb[N*64 fp32 = 25.6MB] | dis[N] |
    //            rs[N] | pairs[E] (LIVE across all agg passes) | ccnt[NB*16] |
    //            cstart[NB] | fmt
    // blockbase (A1G*NB = 3.2MB, dead after k_cscatter) overlays T16.
    // t2 (0.8MB) overlays Bb start (Bb dead after k_gemm<NH> consumes it).
    short* T16    = (short*)d_ws;
    float* Bb     = (float*)((char*)d_ws + (long long)N * NH * 2);
    float* dis    = Bb + (long long)N * NH;
    float* rs     = dis + N;
    int*   pairs  = (int*)(rs + N);
    int*   ccnt   = pairs + E;
    int*   cstart = ccnt + NB * 16;
    int*   fmt    = cstart + NB;
    int*   blockbase = (int*)T16;                  // A1G*NB ints, overlay
    float2* t2    = (float2*)Bb;

    int nb_g  = (N + 63) / 64;
    int nb_i0 = (NB * 16 + 255) / 256;

    // per-call coarse bucket sort (inputs restored before every call)
    k_init0   <<<nb_i0, 256, 0, stream>>>(ei, fmt, ccnt, NB * 16);
    k_coarse  <<<A1G, 256, 0, stream>>>(ei, fmt, ccnt, blockbase, E, NB);
    k_cscan   <<<1, 1024, 0, stream>>>(ccnt, cstart, NB);
    k_cscatter<<<A1G, 256, 0, stream>>>(ei, fmt, cstart, blockbase, pairs, E, NB);
    k_deg     <<<NB, 256, 0, stream>>>(pairs, ccnt, cstart, dis, N);

    // layer 0 (no activation): fused gemm + rowwise int16 quant -> edge-par agg
    k_gemm<NF><<<nb_g, 256, 0, stream>>>(x, W0, dis, T16, rs, N);
    k_agg<0>  <<<NB, 256, 0, stream>>>(T16, rs, pairs, ccnt, cstart, dis, b0,
                                       W2, Bb, t2, N);

    // layer 1 + fused layer-2 transform (tanh @ W2 in epilogue)
    k_gemm<NH><<<nb_g, 256, 0, stream>>>(Bb, W1, dis, T16, rs, N);
    k_agg<1>  <<<NB, 256, 0, stream>>>(T16, rs, pairs, ccnt, cstart, dis, b1,
                                       W2, Bb, t2, N);

    // layer-2 aggregation + head (edge-parallel)
    k_agg2    <<<NB, 256, 0, stream>>>(t2, pairs, ccnt, cstart, dis, b2, Wc, bc,
                                       out, emb, N);
}

// Round 16
// 334.279 us; speedup vs baseline: 4.9801x; 4.9801x over previous
//
#include <hip/hip_runtime.h>

// GCN forward: 3x GCNConv (128->64->64->2) + linear head (2->16).
// N=100000 nodes, E=1600000 edges (+self-loops handled analytically).
// Preprocessing: two-level LDS bucket sort (avoids the ~24G/s global
// returning-atomic wall). Aggregation: atomic-free FULL-WAVE segment-sum
// gathers (lane = channel) over int16 rows (128B = 2 lines) with per-row
// scales fused into the transform GEMM. TWO NODES PER WAVE, interleaved:
// the per-node prologue chain (esrc batch load -> rs gather) dominates at
// mean degree 17 (round 14: neither VALU nor HBM saturated); interleaving two
// independent nodes overlaps the chains. Edge indices readlane'd to SGPRs
// (SALU/saddr T loads); scales vector-gathered per batch, readlane-broadcast.
// BANNED (measured failures): half-wave/2-rows-per-load gather (~3e-3 absmax
// regardless of dtype, rounds 7-9/11); SGPR-indexed rs[] (s_load scalar-cache
// thrash, round 13); LDS float atomicAdd (CAS-loop storm, 10x, round 15).
// dis[] pre-folded: T'[v]=dis[v]*t[v] => O[i]=dis[i]*(T'[i]+sum T'[s])+b.
// Layer-2 transform (tanh @ W2) fused into layer-1 gather epilogue (k_seg1f);
// layer-2 aggregation + head fused (k_seg2f).

#define NF 128
#define NH 64
#define NPB 256      // nodes per coarse bucket (bucket = dst >> 8)
#define MAXNB 512    // max coarse buckets (N < 131072, matches 17-bit src pack)
#define CAP 6144     // max edges per coarse bucket (mean 4096, >30 sigma)
#define A1G 1024     // grid for coarse count/scatter (must match between them)

// Zero coarse counters + detect int64 vs int32 edge_index layout.
__global__ void k_init0(const int* __restrict__ ei, int* __restrict__ fmt,
                        int* __restrict__ ccnt, int nb16) {
    int i = blockIdx.x * 256 + threadIdx.x;
    if (i < nb16) ccnt[i] = 0;
    if (i == 0) {
        int f = 1;
        #pragma unroll
        for (int k = 1; k < 32; k += 2) if (ei[k] != 0) f = 0;
        *fmt = f;   // 1 => int64 (stride 2 in int32 words), 0 => int32
    }
}

// Coarse count: LDS histogram per block, then reserve per-(block,bucket) space
// with ONE padded global atomic per bucket per block (line-parallel).
__global__ void __launch_bounds__(256) k_coarse(
        const int* __restrict__ ei, const int* __restrict__ fmt,
        int* __restrict__ ccnt, int* __restrict__ blockbase, int E, int NB) {
    __shared__ int h[MAXNB];
    int sh = *fmt;
    for (int i = threadIdx.x; i < NB; i += 256) h[i] = 0;
    __syncthreads();
    for (long long e = (long long)blockIdx.x * 256 + threadIdx.x; e < E;
         e += (long long)A1G * 256) {
        int d = ei[(long long)(E + e) << sh];
        atomicAdd(&h[d >> 8], 1);
    }
    __syncthreads();
    for (int b = threadIdx.x; b < NB; b += 256) {
        int c = h[b];
        int base = (c > 0) ? atomicAdd(&ccnt[b * 16], c) : 0;
        blockbase[(long long)blockIdx.x * NB + b] = base;
    }
}

// Exclusive scan of the NB coarse counts (single block).
__global__ void __launch_bounds__(512) k_cscan(
        const int* __restrict__ ccnt, int* __restrict__ cstart, int NB) {
    __shared__ int s[512];
    int t = threadIdx.x;
    int c = (t < NB) ? ccnt[t * 16] : 0;
    s[t] = c;
    __syncthreads();
    for (int off = 1; off < 512; off <<= 1) {
        int v = s[t];
        int u = (t >= off) ? s[t - off] : 0;
        __syncthreads();
        s[t] = v + u;
        __syncthreads();
    }
    if (t < NB) cstart[t] = s[t] - c;
}

// Coarse scatter: same grid-stride partition as k_coarse, so this block's
// per-bucket totals equal its reservation. Per-bucket write bases staged in
// LDS once. Local ranks via LDS int atomics. Edge packed as src|(dst&255)<<17.
__global__ void __launch_bounds__(256) k_cscatter(
        const int* __restrict__ ei, const int* __restrict__ fmt,
        const int* __restrict__ cstart, const int* __restrict__ blockbase,
        int* __restrict__ pairs, int E, int NB) {
    __shared__ int h[MAXNB];
    __shared__ int bb[MAXNB];
    int sh = *fmt;
    for (int i = threadIdx.x; i < NB; i += 256) {
        h[i] = 0;
        bb[i] = cstart[i] + blockbase[(long long)blockIdx.x * NB + i];
    }
    __syncthreads();
    for (long long e = (long long)blockIdx.x * 256 + threadIdx.x; e < E;
         e += (long long)A1G * 256) {
        int s = ei[(long long)e << sh];
        int d = ei[(long long)(E + e) << sh];
        int b = d >> 8;
        int r = atomicAdd(&h[b], 1);
        pairs[bb[b] + r] = s | ((d & 255) << 17);
    }
}

// Fine sort: one block per coarse bucket, entirely in LDS. Emits cnt/start/dis
// (coalesced) and esrc (scatter within the bucket's contiguous window).
__global__ void __launch_bounds__(256) k_bucket(
        const int* __restrict__ pairs, const int* __restrict__ ccnt,
        const int* __restrict__ cstart, int* __restrict__ esrc,
        int* __restrict__ cnt, int* __restrict__ start, float* __restrict__ dis,
        int N) {
    __shared__ int words[CAP];
    __shared__ unsigned char rk[CAP];
    __shared__ int h[NPB];
    __shared__ int hs[NPB];
    int b = blockIdx.x;
    int cs = cstart[b];
    int ec = ccnt[b * 16];
    if (ec > CAP) ec = CAP;          // memory-safety clamp (P ~ 0 for uniform dst)
    int t = threadIdx.x;
    for (int i = t; i < ec; i += 256) words[i] = pairs[cs + i];
    h[t] = 0;
    __syncthreads();
    for (int i = t; i < ec; i += 256) {
        int ld = words[i] >> 17;
        rk[i] = (unsigned char)atomicAdd(&h[ld], 1);
    }
    __syncthreads();
    int c = h[t];
    hs[t] = c;
    __syncthreads();
    for (int off = 1; off < 256; off <<= 1) {
        int v = hs[t];
        int u = (t >= off) ? hs[t - off] : 0;
        __syncthreads();
        hs[t] = v + u;               // inclusive scan
        __syncthreads();
    }
    int node = b * NPB + t;
    if (node < N) {
        cnt[node] = c;
        start[node] = cs + hs[t] - c;
        dis[node] = rsqrtf(1.0f + (float)c);   // degree includes self-loop
    }
    for (int i = t; i < ec; i += 256) {
        int w = words[i];
        int ld = w >> 17;
        esrc[cs + (hs[ld] - h[ld]) + rk[i]] = w & 0x1FFFF;
    }
}

// T16[n,NH] (int16) = quant_rowwise( dis[n] * (X[n,K] @ W[K,NH]) );
// rs[n] = rowmax/32767. 64 rows/block, 4x4 per thread; per-row max via LDS
// atomicMax across the 16 threads sharing a row (abs values: int cmp valid).
template<int K>
__global__ void __launch_bounds__(256) k_gemm(
        const float* __restrict__ X, const float* __restrict__ W,
        const float* __restrict__ dis, short* __restrict__ T16,
        float* __restrict__ rs, int n) {
    constexpr int KP = K + 4;
    __shared__ float xs[64 * KP];
    __shared__ float Ws[K * NH];
    __shared__ int rmax[64];
    if (threadIdx.x < 64) rmax[threadIdx.x] = 0;
    for (int i = threadIdx.x; i < K * NH / 4; i += 256)
        ((float4*)Ws)[i] = ((const float4*)W)[i];
    long long rowbase = (long long)blockIdx.x * 64;
    const float4* X4 = (const float4*)(X + rowbase * K);
    long long lim4 = ((long long)n * K - rowbase * K) >> 2;  // remaining float4s
    for (int i = threadIdx.x; i < 16 * K; i += 256) {
        float4 v = (i < lim4) ? X4[i] : make_float4(0.f, 0.f, 0.f, 0.f);
        int r = i / (K / 4), kk = (i % (K / 4)) * 4;
        *(float4*)&xs[r * KP + kk] = v;
    }
    __syncthreads();
    int c0 = (threadIdx.x & 15) * 4;
    int r0 = (threadIdx.x >> 4) * 4;
    const float* x0 = &xs[(r0 + 0) * KP];
    const float* x1 = &xs[(r0 + 1) * KP];
    const float* x2 = &xs[(r0 + 2) * KP];
    const float* x3 = &xs[(r0 + 3) * KP];
    float4 a0{0,0,0,0}, a1{0,0,0,0}, a2{0,0,0,0}, a3{0,0,0,0};
    #pragma unroll 4
    for (int k = 0; k < K; ++k) {
        float4 w = *(const float4*)&Ws[k * NH + c0];
        float v0 = x0[k], v1 = x1[k], v2 = x2[k], v3 = x3[k];
        a0.x += v0 * w.x; a0.y += v0 * w.y; a0.z += v0 * w.z; a0.w += v0 * w.w;
        a1.x += v1 * w.x; a1.y += v1 * w.y; a1.z += v1 * w.z; a1.w += v1 * w.w;
        a2.x += v2 * w.x; a2.y += v2 * w.y; a2.z += v2 * w.z; a2.w += v2 * w.w;
        a3.x += v3 * w.x; a3.y += v3 * w.y; a3.z += v3 * w.z; a3.w += v3 * w.w;
    }
    int row = (int)rowbase + r0;
    float d0 = (row + 0 < n) ? dis[row + 0] : 0.0f;
    float d1 = (row + 1 < n) ? dis[row + 1] : 0.0f;
    float d2 = (row + 2 < n) ? dis[row + 2] : 0.0f;
    float d3 = (row + 3 < n) ? dis[row + 3] : 0.0f;
    a0.x *= d0; a0.y *= d0; a0.z *= d0; a0.w *= d0;
    a1.x *= d1; a1.y *= d1; a1.z *= d1; a1.w *= d1;
    a2.x *= d2; a2.y *= d2; a2.z *= d2; a2.w *= d2;
    a3.x *= d3; a3.y *= d3; a3.z *= d3; a3.w *= d3;
    float m0 = fmaxf(fmaxf(fabsf(a0.x), fabsf(a0.y)), fmaxf(fabsf(a0.z), fabsf(a0.w)));
    float m1 = fmaxf(fmaxf(fabsf(a1.x), fabsf(a1.y)), fmaxf(fabsf(a1.z), fabsf(a1.w)));
    float m2 = fmaxf(fmaxf(fabsf(a2.x), fabsf(a2.y)), fmaxf(fabsf(a2.z), fabsf(a2.w)));
    float m3 = fmaxf(fmaxf(fabsf(a3.x), fabsf(a3.y)), fmaxf(fabsf(a3.z), fabsf(a3.w)));
    atomicMax(&rmax[r0 + 0], __float_as_int(m0));
    atomicMax(&rmax[r0 + 1], __float_as_int(m1));
    atomicMax(&rmax[r0 + 2], __float_as_int(m2));
    atomicMax(&rmax[r0 + 3], __float_as_int(m3));
    __syncthreads();
    float M0 = __int_as_float(rmax[r0 + 0]);
    float M1 = __int_as_float(rmax[r0 + 1]);
    float M2 = __int_as_float(rmax[r0 + 2]);
    float M3 = __int_as_float(rmax[r0 + 3]);
    float i0 = 32767.0f / fmaxf(M0, 1e-20f);
    float i1 = 32767.0f / fmaxf(M1, 1e-20f);
    float i2 = 32767.0f / fmaxf(M2, 1e-20f);
    float i3 = 32767.0f / fmaxf(M3, 1e-20f);
    const float ks = 1.0f / 32767.0f;
    if (row + 0 < n) {
        short4 q = { (short)__float2int_rn(a0.x * i0), (short)__float2int_rn(a0.y * i0),
                     (short)__float2int_rn(a0.z * i0), (short)__float2int_rn(a0.w * i0) };
        *(short4*)&T16[(long long)(row + 0) * NH + c0] = q;
        if (c0 == 0) rs[row + 0] = M0 * ks;
    }
    if (row + 1 < n) {
        short4 q = { (short)__float2int_rn(a1.x * i1), (short)__float2int_rn(a1.y * i1),
                     (short)__float2int_rn(a1.z * i1), (short)__float2int_rn(a1.w * i1) };
        *(short4*)&T16[(long long)(row + 1) * NH + c0] = q;
        if (c0 == 0) rs[row + 1] = M1 * ks;
    }
    if (row + 2 < n) {
        short4 q = { (short)__float2int_rn(a2.x * i2), (short)__float2int_rn(a2.y * i2),
                     (short)__float2int_rn(a2.z * i2), (short)__float2int_rn(a2.w * i2) };
        *(short4*)&T16[(long long)(row + 2) * NH + c0] = q;
        if (c0 == 0) rs[row + 2] = M2 * ks;
    }
    if (row + 3 < n) {
        short4 q = { (short)__float2int_rn(a3.x * i3), (short)__float2int_rn(a3.y * i3),
                     (short)__float2int_rn(a3.z * i3), (short)__float2int_rn(a3.w * i3) };
        *(short4*)&T16[(long long)(row + 3) * NH + c0] = q;
        if (c0 == 0) rs[row + 3] = M3 * ks;
    }
}

// One A-edge / B-edge step: readlane word+scale bits, saddr int16 load, fma.
#define EDGE_A(J) {                                                           \
    int s_ = __builtin_amdgcn_readlane(sA, (J));                              \
    float f_ = __int_as_float(__builtin_amdgcn_readlane(fAb, (J)));           \
    accA = fmaf(f_, (float)(T + s_ * NH)[lane], accA); }
#define EDGE_B(J) {                                                           \
    int s_ = __builtin_amdgcn_readlane(sB, (J));                              \
    float f_ = __int_as_float(__builtin_amdgcn_readlane(fBb, (J)));           \
    accB = fmaf(f_, (float)(T + s_ * NH)[lane], accB); }

// Full-wave gather, TWO nodes per wave (A,B) with interleaved batches:
// the two batch prologues (esrc load + rs vector-gather) are independent
// chains and overlap; inner loop interleaves 4 A-edges + 4 B-edges.
#define SEG_GATHER2                                                           \
    int lane = threadIdx.x & 63;                                              \
    int na = blockIdx.x * 8 + (threadIdx.x >> 6) * 2;                         \
    int nb_ = na + 1;                                                         \
    if (na >= n) return;                                                      \
    bool hasB = (nb_ < n);                                                    \
    float dia = dis[na];                                                      \
    float dib = hasB ? dis[nb_] : 0.0f;                                       \
    int ga = cnt[na], sta = start[na];                                        \
    int gb = hasB ? cnt[nb_] : 0;                                             \
    int stb = hasB ? start[nb_] : 0;                                          \
    float accA = rs[na] * (float)T[na * NH + lane];                           \
    float accB = hasB ? rs[nb_] * (float)T[nb_ * NH + lane] : 0.0f;           \
    int gmax = ga > gb ? ga : gb;                                             \
    for (int base = 0; base < gmax; base += 64) {                             \
        int ma = ga - base; ma = ma < 0 ? 0 : (ma > 64 ? 64 : ma);            \
        int mb = gb - base; mb = mb < 0 ? 0 : (mb > 64 ? 64 : mb);            \
        int sA = 0, sB = 0; float fA = 0.0f, fB = 0.0f;                       \
        if (lane < ma) { sA = esrc[sta + base + lane]; fA = rs[sA]; }         \
        if (lane < mb) { sB = esrc[stb + base + lane]; fB = rs[sB]; }         \
        int fAb = __float_as_int(fA), fBb = __float_as_int(fB);               \
        int mmin = ma < mb ? ma : mb;                                         \
        int j = 0;                                                            \
        for (; j + 3 < mmin; j += 4) {                                        \
            EDGE_A(j + 0) EDGE_B(j + 0)                                       \
            EDGE_A(j + 1) EDGE_B(j + 1)                                       \
            EDGE_A(j + 2) EDGE_B(j + 2)                                       \
            EDGE_A(j + 3) EDGE_B(j + 3)                                       \
        }                                                                     \
        int jA = j, jB = j;                                                   \
        for (; jA + 3 < ma; jA += 4) {                                        \
            EDGE_A(jA + 0) EDGE_A(jA + 1) EDGE_A(jA + 2) EDGE_A(jA + 3)       \
        }                                                                     \
        for (; jA < ma; ++jA) EDGE_A(jA)                                      \
        for (; jB + 3 < mb; jB += 4) {                                        \
            EDGE_B(jB + 0) EDGE_B(jB + 1) EDGE_B(jB + 2) EDGE_B(jB + 3)       \
        }                                                                     \
        for (; jB < mb; ++jB) EDGE_B(jB)                                      \
    }

// Layer-0: O = di*acc + b for both nodes.
__global__ void __launch_bounds__(256) k_seg(
        const short* __restrict__ T, const float* __restrict__ rs,
        const int* __restrict__ esrc, const int* __restrict__ start,
        const int* __restrict__ cnt, const float* __restrict__ dis,
        const float* __restrict__ b, float* __restrict__ O, int n) {
    SEG_GATHER2
    float bv = b[lane];
    O[(long long)na * NH + lane] = dia * accA + bv;
    if (hasB) O[(long long)nb_ * NH + lane] = dib * accB + bv;
}

// Layer-1 + fused layer-2 transform for both nodes: z1[c]=di*acc+b1[c];
// t=tanh(z1); t2 = di*(t @ W2) via 6-step full-wave butterfly (per node).
__global__ void __launch_bounds__(256) k_seg1f(
        const short* __restrict__ T, const float* __restrict__ rs,
        const int* __restrict__ esrc, const int* __restrict__ start,
        const int* __restrict__ cnt, const float* __restrict__ dis,
        const float* __restrict__ b1, const float* __restrict__ W2,
        float2* __restrict__ t2, int n) {
    SEG_GATHER2
    float bv = b1[lane];
    float2 w = ((const float2*)W2)[lane];   // W2[lane][0], W2[lane][1]
    float tA = tanhf(dia * accA + bv);
    float p0 = tA * w.x, p1 = tA * w.y;
    float tB = hasB ? tanhf(dib * accB + bv) : 0.0f;
    float q0 = tB * w.x, q1 = tB * w.y;
    #pragma unroll
    for (int msk = 32; msk; msk >>= 1) {
        p0 += __shfl_xor(p0, msk, 64);
        p1 += __shfl_xor(p1, msk, 64);
        q0 += __shfl_xor(q0, msk, 64);
        q1 += __shfl_xor(q1, msk, 64);
    }
    if (lane == 0) {
        t2[na] = make_float2(dia * p0, dia * p1);
        if (hasB) t2[nb_] = make_float2(dib * q0, dib * q1);
    }
}

// Fused layer-2 aggregation + head: agg2 = di*(t2[i]+sum t2[s]) + b2;
// emb = tanh(agg2); out = emb @ Wc + bc.
__global__ void __launch_bounds__(256) k_seg2f(
        const float2* __restrict__ T2, const int* __restrict__ esrc,
        const int* __restrict__ start, const int* __restrict__ cnt,
        const float* __restrict__ dis, const float* __restrict__ b2,
        const float* __restrict__ Wc, const float* __restrict__ bc,
        float* __restrict__ out, float* __restrict__ emb, int n) {
    __shared__ float Wcs[32];
    __shared__ float bcs[16];
    if (threadIdx.x < 32) Wcs[threadIdx.x] = Wc[threadIdx.x];
    if (threadIdx.x < 16) bcs[threadIdx.x] = bc[threadIdx.x];
    __syncthreads();
    int i = blockIdx.x * 256 + threadIdx.x;
    if (i >= n) return;
    float di = dis[i];
    int g = cnt[i], st = start[i];
    float2 self = T2[i];
    float a0 = self.x, a1 = self.y;
    int j = 0;
    for (; j + 7 < g; j += 8) {
        int e0 = esrc[st+j],   e1 = esrc[st+j+1], e2 = esrc[st+j+2], e3 = esrc[st+j+3];
        int e4 = esrc[st+j+4], e5 = esrc[st+j+5], e6 = esrc[st+j+6], e7 = esrc[st+j+7];
        float2 v0 = T2[e0], v1 = T2[e1], v2 = T2[e2], v3 = T2[e3];
        float2 v4 = T2[e4], v5 = T2[e5], v6 = T2[e6], v7 = T2[e7];
        a0 += v0.x + v1.x + v2.x + v3.x + v4.x + v5.x + v6.x + v7.x;
        a1 += v0.y + v1.y + v2.y + v3.y + v4.y + v5.y + v6.y + v7.y;
    }
    for (; j < g; ++j) {
        float2 v = T2[esrc[st + j]];
        a0 += v.x; a1 += v.y;
    }
    float e0 = tanhf(a0 * di + b2[0]);
    float e1 = tanhf(a1 * di + b2[1]);
    *(float2*)&emb[(long long)i * 2] = make_float2(e0, e1);
    float* op = &out[(long long)i * 16];
    #pragma unroll
    for (int c4 = 0; c4 < 4; ++c4) {
        float4 o;
        o.x = e0 * Wcs[c4*4+0] + e1 * Wcs[16 + c4*4+0] + bcs[c4*4+0];
        o.y = e0 * Wcs[c4*4+1] + e1 * Wcs[16 + c4*4+1] + bcs[c4*4+1];
        o.z = e0 * Wcs[c4*4+2] + e1 * Wcs[16 + c4*4+2] + bcs[c4*4+2];
        o.w = e0 * Wcs[c4*4+3] + e1 * Wcs[16 + c4*4+3] + bcs[c4*4+3];
        *(float4*)&op[c4 * 4] = o;
    }
}

extern "C" void kernel_launch(void* const* d_in, const int* in_sizes, int n_in,
                              void* d_out, int out_size, void* d_ws, size_t ws_size,
                              hipStream_t stream) {
    const float* x  = (const float*)d_in[0];
    const int*   ei = (const int*)  d_in[1];
    const float* W0 = (const float*)d_in[2];
    const float* b0 = (const float*)d_in[3];
    const float* W1 = (const float*)d_in[4];
    const float* b1 = (const float*)d_in[5];
    const float* W2 = (const float*)d_in[6];
    const float* b2 = (const float*)d_in[7];
    const float* Wc = (const float*)d_in[8];
    const float* bc = (const float*)d_in[9];

    int N = in_sizes[0] / NF;
    int E = in_sizes[1] / 2;
    int NB = (N + NPB - 1) / NPB;   // 391 for N=100000 (must be <= MAXNB)

    float* out = (float*)d_out;                    // [N,16]
    float* emb = out + (long long)N * 16;          // [N,2]

    // workspace: T16[N*64 int16 = 12.8MB] | Bb[N*64 fp32] | dis[N] | rs[N] |
    //            cnt[N] | start[N] | esrc[E] | fmt
    // Preprocessing scratch (pairs/blockbase/ccnt/cstart ~ 8MB) overlays T16
    // (dead until the first k_gemm). t2 (0.8MB) lives at the start of Bb
    // (Bb dead after k_gemm<NH> consumes it; k_seg1f reads T16, writes t2).
    short* T16    = (short*)d_ws;
    float* Bb     = (float*)((char*)d_ws + (long long)N * NH * 2);
    float* dis    = Bb + (long long)N * NH;
    float* rs     = dis + N;
    int*   cnt    = (int*)(rs + N);
    int*   start  = cnt + N;
    int*   esrc   = start + N;
    int*   fmt    = esrc + E;
    float2* t2    = (float2*)Bb;

    int* pairs     = (int*)d_ws;                       // E ints (overlay T16)
    int* blockbase = pairs + E;                        // A1G * NB
    int* ccnt      = blockbase + (long long)A1G * NB;  // NB*16 (line-padded)
    int* cstart    = ccnt + NB * 16;                   // NB

    int nb_n  = (N + 255) / 256;
    int nb_g  = (N + 63) / 64;
    int nb_s2 = (N + 7) / 8;
    int nb_i0 = (NB * 16 + 255) / 256;

    // per-call two-level bucket sort (inputs restored before every call)
    k_init0   <<<nb_i0, 256, 0, stream>>>(ei, fmt, ccnt, NB * 16);
    k_coarse  <<<A1G, 256, 0, stream>>>(ei, fmt, ccnt, blockbase, E, NB);
    k_cscan   <<<1, 512, 0, stream>>>(ccnt, cstart, NB);
    k_cscatter<<<A1G, 256, 0, stream>>>(ei, fmt, cstart, blockbase, pairs, E, NB);
    k_bucket  <<<NB, 256, 0, stream>>>(pairs, ccnt, cstart, esrc, cnt, start, dis, N);

    // layer 0 (no activation): fused gemm + rowwise int16 quant -> gather-sum
    k_gemm<NF><<<nb_g, 256, 0, stream>>>(x, W0, dis, T16, rs, N);
    k_seg     <<<nb_s2, 256, 0, stream>>>(T16, rs, esrc, start, cnt, dis, b0, Bb, N);

    // layer 1 + fused layer-2 transform (tanh + @W2 in gather epilogue)
    k_gemm<NH><<<nb_g, 256, 0, stream>>>(Bb, W1, dis, T16, rs, N);
    k_seg1f   <<<nb_s2, 256, 0, stream>>>(T16, rs, esrc, start, cnt, dis, b1, W2,
                                          t2, N);

    // layer-2 aggregation + head
    k_seg2f   <<<nb_n, 256, 0, stream>>>(t2, esrc, start, cnt, dis, b2, Wc, bc,
                                         out, emb, N);
}

// Round 17
// 333.527 us; speedup vs baseline: 4.9913x; 1.0023x over previous
//
#include <hip/hip_runtime.h>

// GCN forward: 3x GCNConv (128->64->64->2) + linear head (2->16).
// N=100000 nodes, E=1600000 edges (+self-loops handled analytically).
// Preprocessing: two-level LDS bucket sort (avoids the ~24G/s global
// returning-atomic wall). Aggregation: atomic-free FULL-WAVE segment-sum
// gathers (lane = channel) over int16 rows (128B = 2 lines) with per-row
// scales fused into the transform GEMM; TWO nodes per wave interleaved
// (overlaps the per-node prologue chains - round 16: 364->334us).
// Transform GEMM: k-unrolled x4 with float4 LDS reads (round 16 profile:
// 750k bank conflicts + 35cyc-LDS vs 32cyc-VALU per wave-k made the LDS
// pipe binding at 2 blocks/CU occupancy).
// BANNED (measured failures): half-wave/2-rows-per-load gather (~3e-3 absmax
// regardless of dtype, rounds 7-9/11); SGPR-indexed rs[] (s_load scalar-cache
// thrash, round 13); LDS float atomicAdd (CAS-loop storm, 10x, round 15).
// dis[] pre-folded: T'[v]=dis[v]*t[v] => O[i]=dis[i]*(T'[i]+sum T'[s])+b.
// Layer-2 transform (tanh @ W2) fused into layer-1 gather epilogue (k_seg1f);
// layer-2 aggregation + head fused (k_seg2f).

#define NF 128
#define NH 64
#define NPB 256      // nodes per coarse bucket (bucket = dst >> 8)
#define MAXNB 512    // max coarse buckets (N < 131072, matches 17-bit src pack)
#define CAP 6144     // max edges per coarse bucket (mean 4096, >30 sigma)
#define A1G 1024     // grid for coarse count/scatter (must match between them)

// Zero coarse counters + detect int64 vs int32 edge_index layout.
__global__ void k_init0(const int* __restrict__ ei, int* __restrict__ fmt,
                        int* __restrict__ ccnt, int nb16) {
    int i = blockIdx.x * 256 + threadIdx.x;
    if (i < nb16) ccnt[i] = 0;
    if (i == 0) {
        int f = 1;
        #pragma unroll
        for (int k = 1; k < 32; k += 2) if (ei[k] != 0) f = 0;
        *fmt = f;   // 1 => int64 (stride 2 in int32 words), 0 => int32
    }
}

// Coarse count: LDS histogram per block, then reserve per-(block,bucket) space
// with ONE padded global atomic per bucket per block (line-parallel).
__global__ void __launch_bounds__(256) k_coarse(
        const int* __restrict__ ei, const int* __restrict__ fmt,
        int* __restrict__ ccnt, int* __restrict__ blockbase, int E, int NB) {
    __shared__ int h[MAXNB];
    int sh = *fmt;
    for (int i = threadIdx.x; i < NB; i += 256) h[i] = 0;
    __syncthreads();
    for (long long e = (long long)blockIdx.x * 256 + threadIdx.x; e < E;
         e += (long long)A1G * 256) {
        int d = ei[(long long)(E + e) << sh];
        atomicAdd(&h[d >> 8], 1);
    }
    __syncthreads();
    for (int b = threadIdx.x; b < NB; b += 256) {
        int c = h[b];
        int base = (c > 0) ? atomicAdd(&ccnt[b * 16], c) : 0;
        blockbase[(long long)blockIdx.x * NB + b] = base;
    }
}

// Exclusive scan of the NB coarse counts (single block).
__global__ void __launch_bounds__(512) k_cscan(
        const int* __restrict__ ccnt, int* __restrict__ cstart, int NB) {
    __shared__ int s[512];
    int t = threadIdx.x;
    int c = (t < NB) ? ccnt[t * 16] : 0;
    s[t] = c;
    __syncthreads();
    for (int off = 1; off < 512; off <<= 1) {
        int v = s[t];
        int u = (t >= off) ? s[t - off] : 0;
        __syncthreads();
        s[t] = v + u;
        __syncthreads();
    }
    if (t < NB) cstart[t] = s[t] - c;
}

// Coarse scatter: same grid-stride partition as k_coarse, so this block's
// per-bucket totals equal its reservation. Per-bucket write bases staged in
// LDS once. Local ranks via LDS int atomics. Edge packed as src|(dst&255)<<17.
__global__ void __launch_bounds__(256) k_cscatter(
        const int* __restrict__ ei, const int* __restrict__ fmt,
        const int* __restrict__ cstart, const int* __restrict__ blockbase,
        int* __restrict__ pairs, int E, int NB) {
    __shared__ int h[MAXNB];
    __shared__ int bb[MAXNB];
    int sh = *fmt;
    for (int i = threadIdx.x; i < NB; i += 256) {
        h[i] = 0;
        bb[i] = cstart[i] + blockbase[(long long)blockIdx.x * NB + i];
    }
    __syncthreads();
    for (long long e = (long long)blockIdx.x * 256 + threadIdx.x; e < E;
         e += (long long)A1G * 256) {
        int s = ei[(long long)e << sh];
        int d = ei[(long long)(E + e) << sh];
        int b = d >> 8;
        int r = atomicAdd(&h[b], 1);
        pairs[bb[b] + r] = s | ((d & 255) << 17);
    }
}

// Fine sort: one block per coarse bucket, entirely in LDS. Emits cnt/start/dis
// (coalesced) and esrc (scatter within the bucket's contiguous window).
__global__ void __launch_bounds__(256) k_bucket(
        const int* __restrict__ pairs, const int* __restrict__ ccnt,
        const int* __restrict__ cstart, int* __restrict__ esrc,
        int* __restrict__ cnt, int* __restrict__ start, float* __restrict__ dis,
        int N) {
    __shared__ int words[CAP];
    __shared__ unsigned char rk[CAP];
    __shared__ int h[NPB];
    __shared__ int hs[NPB];
    int b = blockIdx.x;
    int cs = cstart[b];
    int ec = ccnt[b * 16];
    if (ec > CAP) ec = CAP;          // memory-safety clamp (P ~ 0 for uniform dst)
    int t = threadIdx.x;
    for (int i = t; i < ec; i += 256) words[i] = pairs[cs + i];
    h[t] = 0;
    __syncthreads();
    for (int i = t; i < ec; i += 256) {
        int ld = words[i] >> 17;
        rk[i] = (unsigned char)atomicAdd(&h[ld], 1);
    }
    __syncthreads();
    int c = h[t];
    hs[t] = c;
    __syncthreads();
    for (int off = 1; off < 256; off <<= 1) {
        int v = hs[t];
        int u = (t >= off) ? hs[t - off] : 0;
        __syncthreads();
        hs[t] = v + u;               // inclusive scan
        __syncthreads();
    }
    int node = b * NPB + t;
    if (node < N) {
        cnt[node] = c;
        start[node] = cs + hs[t] - c;
        dis[node] = rsqrtf(1.0f + (float)c);   // degree includes self-loop
    }
    for (int i = t; i < ec; i += 256) {
        int w = words[i];
        int ld = w >> 17;
        esrc[cs + (hs[ld] - h[ld]) + rk[i]] = w & 0x1FFFF;
    }
}

// T16[n,NH] (int16) = quant_rowwise( dis[n] * (X[n,K] @ W[K,NH]) );
// rs[n] = rowmax/32767. 64 rows/block, 4x4 per thread; k-unrolled x4 with
// float4 LDS reads (8 b128 per 64 FMAs -> VALU-bound, not LDS-bound).
// Per-row max via LDS atomicMax across the 16 threads sharing a row.
template<int K>
__global__ void __launch_bounds__(256) k_gemm(
        const float* __restrict__ X, const float* __restrict__ W,
        const float* __restrict__ dis, short* __restrict__ T16,
        float* __restrict__ rs, int n) {
    constexpr int KP = K + 4;
    __shared__ float xs[64 * KP];
    __shared__ float Ws[K * NH];
    __shared__ int rmax[64];
    if (threadIdx.x < 64) rmax[threadIdx.x] = 0;
    for (int i = threadIdx.x; i < K * NH / 4; i += 256)
        ((float4*)Ws)[i] = ((const float4*)W)[i];
    long long rowbase = (long long)blockIdx.x * 64;
    const float4* X4 = (const float4*)(X + rowbase * K);
    long long lim4 = ((long long)n * K - rowbase * K) >> 2;  // remaining float4s
    for (int i = threadIdx.x; i < 16 * K; i += 256) {
        float4 v = (i < lim4) ? X4[i] : make_float4(0.f, 0.f, 0.f, 0.f);
        int r = i / (K / 4), kk = (i % (K / 4)) * 4;
        *(float4*)&xs[r * KP + kk] = v;
    }
    __syncthreads();
    int c0 = (threadIdx.x & 15) * 4;
    int r0 = (threadIdx.x >> 4) * 4;
    const float* x0 = &xs[(r0 + 0) * KP];
    const float* x1 = &xs[(r0 + 1) * KP];
    const float* x2 = &xs[(r0 + 2) * KP];
    const float* x3 = &xs[(r0 + 3) * KP];
    float4 a0{0,0,0,0}, a1{0,0,0,0}, a2{0,0,0,0}, a3{0,0,0,0};
    #pragma unroll 4
    for (int k4 = 0; k4 < K / 4; ++k4) {
        float4 xv0 = *(const float4*)(x0 + k4 * 4);
        float4 xv1 = *(const float4*)(x1 + k4 * 4);
        float4 xv2 = *(const float4*)(x2 + k4 * 4);
        float4 xv3 = *(const float4*)(x3 + k4 * 4);
        float4 wa = *(const float4*)&Ws[(k4 * 4 + 0) * NH + c0];
        float4 wb = *(const float4*)&Ws[(k4 * 4 + 1) * NH + c0];
        float4 wc = *(const float4*)&Ws[(k4 * 4 + 2) * NH + c0];
        float4 wd = *(const float4*)&Ws[(k4 * 4 + 3) * NH + c0];
        // k4*4+0
        a0.x += xv0.x * wa.x; a0.y += xv0.x * wa.y; a0.z += xv0.x * wa.z; a0.w += xv0.x * wa.w;
        a1.x += xv1.x * wa.x; a1.y += xv1.x * wa.y; a1.z += xv1.x * wa.z; a1.w += xv1.x * wa.w;
        a2.x += xv2.x * wa.x; a2.y += xv2.x * wa.y; a2.z += xv2.x * wa.z; a2.w += xv2.x * wa.w;
        a3.x += xv3.x * wa.x; a3.y += xv3.x * wa.y; a3.z += xv3.x * wa.z; a3.w += xv3.x * wa.w;
        // k4*4+1
        a0.x += xv0.y * wb.x; a0.y += xv0.y * wb.y; a0.z += xv0.y * wb.z; a0.w += xv0.y * wb.w;
        a1.x += xv1.y * wb.x; a1.y += xv1.y * wb.y; a1.z += xv1.y * wb.z; a1.w += xv1.y * wb.w;
        a2.x += xv2.y * wb.x; a2.y += xv2.y * wb.y; a2.z += xv2.y * wb.z; a2.w += xv2.y * wb.w;
        a3.x += xv3.y * wb.x; a3.y += xv3.y * wb.y; a3.z += xv3.y * wb.z; a3.w += xv3.y * wb.w;
        // k4*4+2
        a0.x += xv0.z * wc.x; a0.y += xv0.z * wc.y; a0.z += xv0.z * wc.z; a0.w += xv0.z * wc.w;
        a1.x += xv1.z * wc.x; a1.y += xv1.z * wc.y; a1.z += xv1.z * wc.z; a1.w += xv1.z * wc.w;
        a2.x += xv2.z * wc.x; a2.y += xv2.z * wc.y; a2.z += xv2.z * wc.z; a2.w += xv2.z * wc.w;
        a3.x += xv3.z * wc.x; a3.y += xv3.z * wc.y; a3.z += xv3.z * wc.z; a3.w += xv3.z * wc.w;
        // k4*4+3
        a0.x += xv0.w * wd.x; a0.y += xv0.w * wd.y; a0.z += xv0.w * wd.z; a0.w += xv0.w * wd.w;
        a1.x += xv1.w * wd.x; a1.y += xv1.w * wd.y; a1.z += xv1.w * wd.z; a1.w += xv1.w * wd.w;
        a2.x += xv2.w * wd.x; a2.y += xv2.w * wd.y; a2.z += xv2.w * wd.z; a2.w += xv2.w * wd.w;
        a3.x += xv3.w * wd.x; a3.y += xv3.w * wd.y; a3.z += xv3.w * wd.z; a3.w += xv3.w * wd.w;
    }
    int row = (int)rowbase + r0;
    float d0 = (row + 0 < n) ? dis[row + 0] : 0.0f;
    float d1 = (row + 1 < n) ? dis[row + 1] : 0.0f;
    float d2 = (row + 2 < n) ? dis[row + 2] : 0.0f;
    float d3 = (row + 3 < n) ? dis[row + 3] : 0.0f;
    a0.x *= d0; a0.y *= d0; a0.z *= d0; a0.w *= d0;
    a1.x *= d1; a1.y *= d1; a1.z *= d1; a1.w *= d1;
    a2.x *= d2; a2.y *= d2; a2.z *= d2; a2.w *= d2;
    a3.x *= d3; a3.y *= d3; a3.z *= d3; a3.w *= d3;
    float m0 = fmaxf(fmaxf(fabsf(a0.x), fabsf(a0.y)), fmaxf(fabsf(a0.z), fabsf(a0.w)));
    float m1 = fmaxf(fmaxf(fabsf(a1.x), fabsf(a1.y)), fmaxf(fabsf(a1.z), fabsf(a1.w)));
    float m2 = fmaxf(fmaxf(fabsf(a2.x), fabsf(a2.y)), fmaxf(fabsf(a2.z), fabsf(a2.w)));
    float m3 = fmaxf(fmaxf(fabsf(a3.x), fabsf(a3.y)), fmaxf(fabsf(a3.z), fabsf(a3.w)));
    atomicMax(&rmax[r0 + 0], __float_as_int(m0));
    atomicMax(&rmax[r0 + 1], __float_as_int(m1));
    atomicMax(&rmax[r0 + 2], __float_as_int(m2));
    atomicMax(&rmax[r0 + 3], __float_as_int(m3));
    __syncthreads();
    float M0 = __int_as_float(rmax[r0 + 0]);
    float M1 = __int_as_float(rmax[r0 + 1]);
    float M2 = __int_as_float(rmax[r0 + 2]);
    float M3 = __int_as_float(rmax[r0 + 3]);
    float i0 = 32767.0f / fmaxf(M0, 1e-20f);
    float i1 = 32767.0f / fmaxf(M1, 1e-20f);
    float i2 = 32767.0f / fmaxf(M2, 1e-20f);
    float i3 = 32767.0f / fmaxf(M3, 1e-20f);
    const float ks = 1.0f / 32767.0f;
    if (row + 0 < n) {
        short4 q = { (short)__float2int_rn(a0.x * i0), (short)__float2int_rn(a0.y * i0),
                     (short)__float2int_rn(a0.z * i0), (short)__float2int_rn(a0.w * i0) };
        *(short4*)&T16[(long long)(row + 0) * NH + c0] = q;
        if (c0 == 0) rs[row + 0] = M0 * ks;
    }
    if (row + 1 < n) {
        short4 q = { (short)__float2int_rn(a1.x * i1), (short)__float2int_rn(a1.y * i1),
                     (short)__float2int_rn(a1.z * i1), (short)__float2int_rn(a1.w * i1) };
        *(short4*)&T16[(long long)(row + 1) * NH + c0] = q;
        if (c0 == 0) rs[row + 1] = M1 * ks;
    }
    if (row + 2 < n) {
        short4 q = { (short)__float2int_rn(a2.x * i2), (short)__float2int_rn(a2.y * i2),
                     (short)__float2int_rn(a2.z * i2), (short)__float2int_rn(a2.w * i2) };
        *(short4*)&T16[(long long)(row + 2) * NH + c0] = q;
        if (c0 == 0) rs[row + 2] = M2 * ks;
    }
    if (row + 3 < n) {
        short4 q = { (short)__float2int_rn(a3.x * i3), (short)__float2int_rn(a3.y * i3),
                     (short)__float2int_rn(a3.z * i3), (short)__float2int_rn(a3.w * i3) };
        *(short4*)&T16[(long long)(row + 3) * NH + c0] = q;
        if (c0 == 0) rs[row + 3] = M3 * ks;
    }
}

// One A-edge / B-edge step: readlane word+scale bits, saddr int16 load, fma.
#define EDGE_A(J) {                                                           \
    int s_ = __builtin_amdgcn_readlane(sA, (J));                              \
    float f_ = __int_as_float(__builtin_amdgcn_readlane(fAb, (J)));           \
    accA = fmaf(f_, (float)(T + s_ * NH)[lane], accA); }
#define EDGE_B(J) {                                                           \
    int s_ = __builtin_amdgcn_readlane(sB, (J));                              \
    float f_ = __int_as_float(__builtin_amdgcn_readlane(fBb, (J)));           \
    accB = fmaf(f_, (float)(T + s_ * NH)[lane], accB); }

// Full-wave gather, TWO nodes per wave (A,B) with interleaved batches:
// the two batch prologues (esrc load + rs vector-gather) are independent
// chains and overlap; inner loop interleaves 4 A-edges + 4 B-edges.
#define SEG_GATHER2                                                           \
    int lane = threadIdx.x & 63;                                              \
    int na = blockIdx.x * 8 + (threadIdx.x >> 6) * 2;                         \
    int nb_ = na + 1;                                                         \
    if (na >= n) return;                                                      \
    bool hasB = (nb_ < n);                                                    \
    float dia = dis[na];                                                      \
    float dib = hasB ? dis[nb_] : 0.0f;                                       \
    int ga = cnt[na], sta = start[na];                                        \
    int gb = hasB ? cnt[nb_] : 0;                                             \
    int stb = hasB ? start[nb_] : 0;                                          \
    float accA = rs[na] * (float)T[na * NH + lane];                           \
    float accB = hasB ? rs[nb_] * (float)T[nb_ * NH + lane] : 0.0f;           \
    int gmax = ga > gb ? ga : gb;                                             \
    for (int base = 0; base < gmax; base += 64) {                             \
        int ma = ga - base; ma = ma < 0 ? 0 : (ma > 64 ? 64 : ma);            \
        int mb = gb - base; mb = mb < 0 ? 0 : (mb > 64 ? 64 : mb);            \
        int sA = 0, sB = 0; float fA = 0.0f, fB = 0.0f;                       \
        if (lane < ma) { sA = esrc[sta + base + lane]; fA = rs[sA]; }         \
        if (lane < mb) { sB = esrc[stb + base + lane]; fB = rs[sB]; }         \
        int fAb = __float_as_int(fA), fBb = __float_as_int(fB);               \
        int mmin = ma < mb ? ma : mb;                                         \
        int j = 0;                                                            \
        for (; j + 3 < mmin; j += 4) {                                        \
            EDGE_A(j + 0) EDGE_B(j + 0)                                       \
            EDGE_A(j + 1) EDGE_B(j + 1)                                       \
            EDGE_A(j + 2) EDGE_B(j + 2)                                       \
            EDGE_A(j + 3) EDGE_B(j + 3)                                       \
        }                                                                     \
        int jA = j, jB = j;                                                   \
        for (; jA + 3 < ma; jA += 4) {                                        \
            EDGE_A(jA + 0) EDGE_A(jA + 1) EDGE_A(jA + 2) EDGE_A(jA + 3)       \
        }                                                                     \
        for (; jA < ma; ++jA) EDGE_A(jA)                                      \
        for (; jB + 3 < mb; jB += 4) {                                        \
            EDGE_B(jB + 0) EDGE_B(jB + 1) EDGE_B(jB + 2) EDGE_B(jB + 3)       \
        }                                                                     \
        for (; jB < mb; ++jB) EDGE_B(jB)                                      \
    }

// Layer-0: O = di*acc + b for both nodes.
__global__ void __launch_bounds__(256) k_seg(
        const short* __restrict__ T, const float* __restrict__ rs,
        const int* __restrict__ esrc, const int* __restrict__ start,
        const int* __restrict__ cnt, const float* __restrict__ dis,
        const float* __restrict__ b, float* __restrict__ O, int n) {
    SEG_GATHER2
    float bv = b[lane];
    O[(long long)na * NH + lane] = dia * accA + bv;
    if (hasB) O[(long long)nb_ * NH + lane] = dib * accB + bv;
}

// Layer-1 + fused layer-2 transform for both nodes: z1[c]=di*acc+b1[c];
// t=tanh(z1); t2 = di*(t @ W2) via 6-step full-wave butterfly (per node).
__global__ void __launch_bounds__(256) k_seg1f(
        const short* __restrict__ T, const float* __restrict__ rs,
        const int* __restrict__ esrc, const int* __restrict__ start,
        const int* __restrict__ cnt, const float* __restrict__ dis,
        const float* __restrict__ b1, const float* __restrict__ W2,
        float2* __restrict__ t2, int n) {
    SEG_GATHER2
    float bv = b1[lane];
    float2 w = ((const float2*)W2)[lane];   // W2[lane][0], W2[lane][1]
    float tA = tanhf(dia * accA + bv);
    float p0 = tA * w.x, p1 = tA * w.y;
    float tB = hasB ? tanhf(dib * accB + bv) : 0.0f;
    float q0 = tB * w.x, q1 = tB * w.y;
    #pragma unroll
    for (int msk = 32; msk; msk >>= 1) {
        p0 += __shfl_xor(p0, msk, 64);
        p1 += __shfl_xor(p1, msk, 64);
        q0 += __shfl_xor(q0, msk, 64);
        q1 += __shfl_xor(q1, msk, 64);
    }
    if (lane == 0) {
        t2[na] = make_float2(dia * p0, dia * p1);
        if (hasB) t2[nb_] = make_float2(dib * q0, dib * q1);
    }
}

// Fused layer-2 aggregation + head: agg2 = di*(t2[i]+sum t2[s]) + b2;
// emb = tanh(agg2); out = emb @ Wc + bc.
__global__ void __launch_bounds__(256) k_seg2f(
        const float2* __restrict__ T2, const int* __restrict__ esrc,
        const int* __restrict__ start, const int* __restrict__ cnt,
        const float* __restrict__ dis, const float* __restrict__ b2,
        const float* __restrict__ Wc, const float* __restrict__ bc,
        float* __restrict__ out, float* __restrict__ emb, int n) {
    __shared__ float Wcs[32];
    __shared__ float bcs[16];
    if (threadIdx.x < 32) Wcs[threadIdx.x] = Wc[threadIdx.x];
    if (threadIdx.x < 16) bcs[threadIdx.x] = bc[threadIdx.x];
    __syncthreads();
    int i = blockIdx.x * 256 + threadIdx.x;
    if (i >= n) return;
    float di = dis[i];
    int g = cnt[i], st = start[i];
    float2 self = T2[i];
    float a0 = self.x, a1 = self.y;
    int j = 0;
    for (; j + 7 < g; j += 8) {
        int e0 = esrc[st+j],   e1 = esrc[st+j+1], e2 = esrc[st+j+2], e3 = esrc[st+j+3];
        int e4 = esrc[st+j+4], e5 = esrc[st+j+5], e6 = esrc[st+j+6], e7 = esrc[st+j+7];
        float2 v0 = T2[e0], v1 = T2[e1], v2 = T2[e2], v3 = T2[e3];
        float2 v4 = T2[e4], v5 = T2[e5], v6 = T2[e6], v7 = T2[e7];
        a0 += v0.x + v1.x + v2.x + v3.x + v4.x + v5.x + v6.x + v7.x;
        a1 += v0.y + v1.y + v2.y + v3.y + v4.y + v5.y + v6.y + v7.y;
    }
    for (; j < g; ++j) {
        float2 v = T2[esrc[st + j]];
        a0 += v.x; a1 += v.y;
    }
    float e0 = tanhf(a0 * di + b2[0]);
    float e1 = tanhf(a1 * di + b2[1]);
    *(float2*)&emb[(long long)i * 2] = make_float2(e0, e1);
    float* op = &out[(long long)i * 16];
    #pragma unroll
    for (int c4 = 0; c4 < 4; ++c4) {
        float4 o;
        o.x = e0 * Wcs[c4*4+0] + e1 * Wcs[16 + c4*4+0] + bcs[c4*4+0];
        o.y = e0 * Wcs[c4*4+1] + e1 * Wcs[16 + c4*4+1] + bcs[c4*4+1];
        o.z = e0 * Wcs[c4*4+2] + e1 * Wcs[16 + c4*4+2] + bcs[c4*4+2];
        o.w = e0 * Wcs[c4*4+3] + e1 * Wcs[16 + c4*4+3] + bcs[c4*4+3];
        *(float4*)&op[c4 * 4] = o;
    }
}

extern "C" void kernel_launch(void* const* d_in, const int* in_sizes, int n_in,
                              void* d_out, int out_size, void* d_ws, size_t ws_size,
                              hipStream_t stream) {
    const float* x  = (const float*)d_in[0];
    const int*   ei = (const int*)  d_in[1];
    const float* W0 = (const float*)d_in[2];
    const float* b0 = (const float*)d_in[3];
    const float* W1 = (const float*)d_in[4];
    const float* b1 = (const float*)d_in[5];
    const float* W2 = (const float*)d_in[6];
    const float* b2 = (const float*)d_in[7];
    const float* Wc = (const float*)d_in[8];
    const float* bc = (const float*)d_in[9];

    int N = in_sizes[0] / NF;
    int E = in_sizes[1] / 2;
    int NB = (N + NPB - 1) / NPB;   // 391 for N=100000 (must be <= MAXNB)

    float* out = (float*)d_out;                    // [N,16]
    float* emb = out + (long long)N * 16;          // [N,2]

    // workspace: T16[N*64 int16 = 12.8MB] | Bb[N*64 fp32] | dis[N] | rs[N] |
    //            cnt[N] | start[N] | esrc[E] | fmt
    // Preprocessing scratch (pairs/blockbase/ccnt/cstart ~ 8MB) overlays T16
    // (dead until the first k_gemm). t2 (0.8MB) lives at the start of Bb
    // (Bb dead after k_gemm<NH> consumes it; k_seg1f reads T16, writes t2).
    short* T16    = (short*)d_ws;
    float* Bb     = (float*)((char*)d_ws + (long long)N * NH * 2);
    float* dis    = Bb + (long long)N * NH;
    float* rs     = dis + N;
    int*   cnt    = (int*)(rs + N);
    int*   start  = cnt + N;
    int*   esrc   = start + N;
    int*   fmt    = esrc + E;
    float2* t2    = (float2*)Bb;

    int* pairs     = (int*)d_ws;                       // E ints (overlay T16)
    int* blockbase = pairs + E;                        // A1G * NB
    int* ccnt      = blockbase + (long long)A1G * NB;  // NB*16 (line-padded)
    int* cstart    = ccnt + NB * 16;                   // NB

    int nb_n  = (N + 255) / 256;
    int nb_g  = (N + 63) / 64;
    int nb_s2 = (N + 7) / 8;
    int nb_i0 = (NB * 16 + 255) / 256;

    // per-call two-level bucket sort (inputs restored before every call)
    k_init0   <<<nb_i0, 256, 0, stream>>>(ei, fmt, ccnt, NB * 16);
    k_coarse  <<<A1G, 256, 0, stream>>>(ei, fmt, ccnt, blockbase, E, NB);
    k_cscan   <<<1, 512, 0, stream>>>(ccnt, cstart, NB);
    k_cscatter<<<A1G, 256, 0, stream>>>(ei, fmt, cstart, blockbase, pairs, E, NB);
    k_bucket  <<<NB, 256, 0, stream>>>(pairs, ccnt, cstart, esrc, cnt, start, dis, N);

    // layer 0 (no activation): fused gemm + rowwise int16 quant -> gather-sum
    k_gemm<NF><<<nb_g, 256, 0, stream>>>(x, W0, dis, T16, rs, N);
    k_seg     <<<nb_s2, 256, 0, stream>>>(T16, rs, esrc, start, cnt, dis, b0, Bb, N);

    // layer 1 + fused layer-2 transform (tanh + @W2 in gather epilogue)
    k_gemm<NH><<<nb_g, 256, 0, stream>>>(Bb, W1, dis, T16, rs, N);
    k_seg1f   <<<nb_s2, 256, 0, stream>>>(T16, rs, esrc, start, cnt, dis, b1, W2,
                                          t2, N);

    // layer-2 aggregation + head
    k_seg2f   <<<nb_n, 256, 0, stream>>>(t2, esrc, start, cnt, dis, b2, Wc, bc,
                                         out, emb, N);
}